// Round 4
// baseline (314.949 us; speedup 1.0000x reference)
//
#include <hip/hip_runtime.h>

#define NB 32
#define W 512
#define H 512
#define TX 54          // output cols per block (region = 64 = one wave of lanes)
#define TY 32          // output rows per block (4 waves x 8-row chunks)
#define BLOCK 256
#define SP 65          // scr pitch (65%32=1 -> <=2-way banks everywhere, free)
#define GRIDX 10       // ceil(512/54)
#define C2f 0.0009f

// normalized gaussian(11, sigma=1.5)
#define GW0 0.001028381f
#define GW1 0.007598758f
#define GW2 0.036000773f
#define GW3 0.109360700f
#define GW4 0.213005540f
#define GW5 0.266011720f

__device__ __forceinline__ float gwv(int k) {
    const float g[11] = {GW0, GW1, GW2, GW3, GW4, GW5, GW4, GW3, GW2, GW1, GW0};
    return g[k];
}

template<bool GUARD>
__device__ __forceinline__ float ld(const float* __restrict__ p, int gy, int gx) {
    if (GUARD) {
        bool ok = ((unsigned)gx < W) && ((unsigned)gy < H);
        int cy = min(max(gy, 0), H - 1);
        int cx = min(max(gx, 0), W - 1);
        float v = p[cy * W + cx];
        return ok ? v : 0.f;  // zero-pad semantics
    }
    return p[gy * W + gx];
}

// Vertical 11-tap gaussian, lane = region column (coalesced), wave = 8-row
// chunk, circular register window (no shift movs after full unroll).
// PHASE 0: {mu1(g), mu2(i), mu3(v), c11(g*g)} + fused sobel/intensity:
//   sobel is separable; its 3-tap vertical windows are subsets of the 11-row
//   window already in registers; horizontal +-1 via __shfl. Zero extra loads.
// PHASE 1: {c22(i*i), c33(v*v), c12(g*i), c13(g*v)}
template<bool GUARD, int PHASE>
__device__ __forceinline__ void vpass(
    const float* __restrict__ pg, const float* __restrict__ pi,
    const float* __restrict__ pv, float (&scr)[4][TY][SP],
    int x0, int y0, int lane, int wvi,
    float& sum_in, float& sum_grad) {
    const int gx = x0 - 5 + lane;
    const int ytop = y0 + wvi * 8 - 5;
    float a[11], b[11], c[11];
    #pragma unroll
    for (int k = 0; k < 10; ++k) {
        a[k] = ld<GUARD>(pg, ytop + k, gx);
        b[k] = ld<GUARD>(pi, ytop + k, gx);
        c[k] = ld<GUARD>(pv, ytop + k, gx);
    }
    // output column for sobel/intensity is gx itself; gx>=0 guaranteed by lane>=5
    const bool colok = (lane >= 5) && (lane <= 58) && (!GUARD || gx < W);
    #pragma unroll
    for (int r = 0; r < 8; ++r) {
        const int i10 = (r + 10) % 11;
        a[i10] = ld<GUARD>(pg, ytop + 10 + r, gx);
        b[i10] = ld<GUARD>(pi, ytop + 10 + r, gx);
        c[i10] = ld<GUARD>(pv, ytop + 10 + r, gx);
        float q0 = 0.f, q1 = 0.f, q2 = 0.f, q3 = 0.f;
        #pragma unroll
        for (int k = 0; k < 11; ++k) {
            float v1 = a[(r + k) % 11], v2 = b[(r + k) % 11],
                  v3 = c[(r + k) % 11], g = gwv(k);
            if (PHASE == 0) {
                q0 = fmaf(g, v1, q0);
                q1 = fmaf(g, v2, q1);
                q2 = fmaf(g, v3, q2);
                q3 = fmaf(g, v1 * v1, q3);
            } else {
                q0 = fmaf(g, v2 * v2, q0);
                q1 = fmaf(g, v3 * v3, q1);
                q2 = fmaf(g, v1 * v2, q2);
                q3 = fmaf(g, v1 * v3, q3);
            }
        }
        const int rr = wvi * 8 + r;
        scr[0][rr][lane] = q0;
        scr[1][rr][lane] = q1;
        scr[2][rr][lane] = q2;
        scr[3][rr][lane] = q3;
        if (PHASE == 0) {
            const int i4 = (r + 4) % 11, i5 = (r + 5) % 11, i6 = (r + 6) % 11;
            // vertical parts: p = [1,2,1], q = [1,0,-1] (sign-free under abs)
            float pa = a[i4] + 2.f * a[i5] + a[i6], qa = a[i4] - a[i6];
            float pb = b[i4] + 2.f * b[i5] + b[i6], qb = b[i4] - b[i6];
            float pc = c[i4] + 2.f * c[i5] + c[i6], qc = c[i4] - c[i6];
            float pal = __shfl(pa, lane - 1), par = __shfl(pa, lane + 1);
            float qal = __shfl(qa, lane - 1), qar = __shfl(qa, lane + 1);
            float pbl = __shfl(pb, lane - 1), pbr = __shfl(pb, lane + 1);
            float qbl = __shfl(qb, lane - 1), qbr = __shfl(qb, lane + 1);
            float pcl = __shfl(pc, lane - 1), pcr = __shfl(pc, lane + 1);
            float qcl = __shfl(qc, lane - 1), qcr = __shfl(qc, lane + 1);
            float sga = fabsf(par - pal) + fabsf(qal + 2.f * qa + qar);
            float sgb = fabsf(pbr - pbl) + fabsf(qbl + 2.f * qb + qbr);
            float sgc = fabsf(pcr - pcl) + fabsf(qcl + 2.f * qc + qcr);
            if (colok) {
                sum_in   += fabsf(a[i5] - fmaxf(c[i5], b[i5]));
                sum_grad += fabsf(sga - fmaxf(sgc, sgb));
            }
        }
    }
}

// horizontal 11-tap: thread owns (row, 7-output chunk), circular window.
// chunk 7 overlaps chunk 6 (xb clamped to 47 so reads stay < 64); its j<2
// outputs are duplicates and masked out at accumulation.
__device__ __forceinline__ void hpass(const float (&scr)[4][TY][SP],
                                      float (&res)[4][7], int tid) {
    const int r = tid & 31;
    const int cch = tid >> 5;
    const int xb = (cch < 7) ? cch * 7 : 47;
    #pragma unroll
    for (int q = 0; q < 4; ++q) {
        float w[11];
        #pragma unroll
        for (int k = 0; k < 10; ++k) w[k] = scr[q][r][xb + k];
        #pragma unroll
        for (int j = 0; j < 7; ++j) {
            w[(j + 10) % 11] = scr[q][r][xb + 10 + j];
            float acc = 0.f;
            #pragma unroll
            for (int k = 0; k < 11; ++k)
                acc = fmaf(gwv(k), w[(j + k) % 11], acc);
            res[q][j] = acc;
        }
    }
}

template<bool GUARD>
__device__ __forceinline__ void body(
    const float* __restrict__ pv, const float* __restrict__ pi,
    const float* __restrict__ pg, float (&scr)[4][TY][SP],
    float (&red)[3][4], int x0, int y0, double* __restrict__ sums) {
    const int tid = threadIdx.x;
    const int lane = tid & 63;
    const int wvi = tid >> 6;
    float sum_in = 0.f, sum_grad = 0.f, sum_ssim = 0.f;

    float resA[4][7], resB[4][7];
    vpass<GUARD, 0>(pg, pi, pv, scr, x0, y0, lane, wvi, sum_in, sum_grad);
    __syncthreads();
    hpass(scr, resA, tid);
    __syncthreads();
    vpass<GUARD, 1>(pg, pi, pv, scr, x0, y0, lane, wvi, sum_in, sum_grad);
    __syncthreads();
    hpass(scr, resB, tid);

    const int cch = tid >> 5;
    const int xb = (cch < 7) ? cch * 7 : 47;
    #pragma unroll
    for (int j = 0; j < 7; ++j) {
        bool valid = (cch < 7) || (j >= 2);     // drop chunk-7 duplicates
        if (GUARD) valid = valid && (x0 + xb + j < W);
        float m1 = resA[0][j], m2 = resA[1][j], m3 = resA[2][j];
        float sig1 = resA[3][j] - m1 * m1;
        float sig2 = resB[0][j] - m2 * m2;
        float sig3 = resB[1][j] - m3 * m3;
        float sg12 = resB[2][j] - m1 * m2;
        float sg13 = resB[3][j] - m1 * m3;
        float x2 = sqrtf(sig2);
        float x3 = sqrtf(sig3);
        float map12 = (2.f * sg12 + C2f) / (sig1 + sig2 + C2f);
        float map13 = (2.f * sg13 + C2f) / (sig1 + sig3 + C2f);
        // matches jnp.where(|x2| >= |x3|, map12, map13); NaN -> map13
        float m = (fabsf(x2) >= fabsf(x3)) ? map12 : map13;
        if (valid) sum_ssim += m;
    }

    // ---- reduce ----
    #pragma unroll
    for (int o = 32; o > 0; o >>= 1) {
        sum_in   += __shfl_down(sum_in, o);
        sum_grad += __shfl_down(sum_grad, o);
        sum_ssim += __shfl_down(sum_ssim, o);
    }
    if (lane == 0) { red[0][wvi] = sum_in; red[1][wvi] = sum_grad; red[2][wvi] = sum_ssim; }
    __syncthreads();
    if (tid == 0) {
        float a = 0.f, b = 0.f, c = 0.f;
        #pragma unroll
        for (int k = 0; k < 4; ++k) { a += red[0][k]; b += red[1][k]; c += red[2][k]; }
        atomicAdd(&sums[0], (double)a);
        atomicAdd(&sums[1], (double)b);
        atomicAdd(&sums[2], (double)c);
    }
}

__global__ __launch_bounds__(BLOCK) void fusion_main(
    const float* __restrict__ vis, const float* __restrict__ ir,
    const float* __restrict__ gen, double* __restrict__ sums) {
    __shared__ float scr[4][TY][SP];   // 4*32*65*4 = 33280 B -> 4 blocks/CU
    __shared__ float red[3][4];
    const size_t off = (size_t)blockIdx.z * (H * W);
    const int x0 = blockIdx.x * TX;
    const int y0 = blockIdx.y * TY;
    const float* pv = vis + off;
    const float* pi = ir + off;
    const float* pg = gen + off;
    // interior: x-range [x0-5, x0+58] within [0,512) and y-range likewise
    bool interior = (blockIdx.x >= 1) && (blockIdx.x <= 8) &&
                    (blockIdx.y >= 1) && (blockIdx.y <= 14);
    if (interior) body<false>(pv, pi, pg, scr, red, x0, y0, sums);
    else          body<true>(pv, pi, pg, scr, red, x0, y0, sums);
}

__global__ void finalize(const double* __restrict__ sums, float* __restrict__ out) {
    const double inv = 1.0 / ((double)NB * H * W);
    out[0] = (float)(1.5 * sums[0] * inv);
    out[1] = (float)(0.5 * (1.0 - sums[2] * inv) + sums[1] * inv);
}

extern "C" void kernel_launch(void* const* d_in, const int* in_sizes, int n_in,
                              void* d_out, int out_size, void* d_ws, size_t ws_size,
                              hipStream_t stream) {
    const float* vis = (const float*)d_in[0];
    const float* ir  = (const float*)d_in[1];
    const float* gen = (const float*)d_in[2];
    float* out = (float*)d_out;
    double* sums = (double*)d_ws;

    hipMemsetAsync(d_ws, 0, 3 * sizeof(double), stream);
    dim3 grid(GRIDX, H / TY, NB);
    fusion_main<<<grid, BLOCK, 0, stream>>>(vis, ir, gen, sums);
    finalize<<<1, 1, 0, stream>>>(sums, out);
}

// Round 5
// 309.441 us; speedup vs baseline: 1.0178x; 1.0178x over previous
//
#include <hip/hip_runtime.h>

#define NB 32
#define W 512
#define H 512
#define TX 54          // output cols per block (region = 64 = one wave)
#define TY 32          // output rows per block (4 waves x 8-row chunks)
#define BLOCK 256
#define SP 65          // pitch: 65%32=1 -> <=2-way LDS banks everywhere (free)
#define GRIDX 10       // ceil(512/54)
#define C2f 0.0009f

// normalized gaussian(11, sigma=1.5)
#define GW0 0.001028381f
#define GW1 0.007598758f
#define GW2 0.036000773f
#define GW3 0.109360700f
#define GW4 0.213005540f
#define GW5 0.266011720f

__device__ __forceinline__ float gwv(int k) {
    const float g[11] = {GW0, GW1, GW2, GW3, GW4, GW5, GW4, GW3, GW2, GW1, GW0};
    return g[k];
}

union SMem {
    float praw[3][34][SP];   // raw pixels, rows y0-1 .. y0+32   (26520 B)
    float scr[4][TY][SP];    // separable-conv vertical results  (33280 B)
};

template<bool GUARD>
__device__ __forceinline__ float ld(const float* __restrict__ p, int gy, int gx) {
    if (GUARD) {
        bool ok = ((unsigned)gx < W) && ((unsigned)gy < H);
        int cy = min(max(gy, 0), H - 1);
        int cx = min(max(gx, 0), W - 1);
        float v = p[cy * W + cx];
        return ok ? v : 0.f;  // zero-pad semantics
    }
    return p[gy * W + gx];
}

// Vertical 11-tap gaussian: lane = region column (coalesced), wave = 8-row
// chunk, circular register window. Pure (no cross-lane ops on the chain).
// PHASE 0: {mu1(g), mu2(i), mu3(v), c11(g*g)}
// PHASE 1: {c22(i*i), c33(v*v), c12(g*i), c13(g*v)}
template<bool GUARD, int PHASE>
__device__ __forceinline__ void vpass(
    const float* __restrict__ pg, const float* __restrict__ pi,
    const float* __restrict__ pv, SMem& sm,
    int x0, int y0, int lane, int wvi) {
    const int gx = x0 - 5 + lane;
    const int ytop = y0 + wvi * 8 - 5;
    float a[11], b[11], c[11];
    #pragma unroll
    for (int k = 0; k < 10; ++k) {
        a[k] = ld<GUARD>(pg, ytop + k, gx);
        b[k] = ld<GUARD>(pi, ytop + k, gx);
        c[k] = ld<GUARD>(pv, ytop + k, gx);
    }
    #pragma unroll
    for (int r = 0; r < 8; ++r) {
        const int i10 = (r + 10) % 11;
        a[i10] = ld<GUARD>(pg, ytop + 10 + r, gx);
        b[i10] = ld<GUARD>(pi, ytop + 10 + r, gx);
        c[i10] = ld<GUARD>(pv, ytop + 10 + r, gx);
        float q0 = 0.f, q1 = 0.f, q2 = 0.f, q3 = 0.f;
        #pragma unroll
        for (int k = 0; k < 11; ++k) {
            float v1 = a[(r + k) % 11], v2 = b[(r + k) % 11],
                  v3 = c[(r + k) % 11], g = gwv(k);
            if (PHASE == 0) {
                q0 = fmaf(g, v1, q0);
                q1 = fmaf(g, v2, q1);
                q2 = fmaf(g, v3, q2);
                q3 = fmaf(g, v1 * v1, q3);
            } else {
                q0 = fmaf(g, v2 * v2, q0);
                q1 = fmaf(g, v3 * v3, q1);
                q2 = fmaf(g, v1 * v2, q2);
                q3 = fmaf(g, v1 * v3, q3);
            }
        }
        const int rr = wvi * 8 + r;
        sm.scr[0][rr][lane] = q0;
        sm.scr[1][rr][lane] = q1;
        sm.scr[2][rr][lane] = q2;
        sm.scr[3][rr][lane] = q3;
    }
}

// horizontal 11-tap: thread owns (row, 7-output chunk), circular window.
// chunk 7 clamps to xb=47 (reads stay < 64); its j<2 outputs are dups, masked.
__device__ __forceinline__ void hpass(const SMem& sm, float (&res)[4][7], int tid) {
    const int r = tid & 31;
    const int cch = tid >> 5;
    const int xb = (cch < 7) ? cch * 7 : 47;
    #pragma unroll
    for (int q = 0; q < 4; ++q) {
        float w[11];
        #pragma unroll
        for (int k = 0; k < 10; ++k) w[k] = sm.scr[q][r][xb + k];
        #pragma unroll
        for (int j = 0; j < 7; ++j) {
            w[(j + 10) % 11] = sm.scr[q][r][xb + 10 + j];
            float acc = 0.f;
            #pragma unroll
            for (int k = 0; k < 11; ++k)
                acc = fmaf(gwv(k), w[(j + k) % 11], acc);
            res[q][j] = acc;
        }
    }
}

template<bool GUARD>
__device__ __forceinline__ void body(
    const float* __restrict__ pv, const float* __restrict__ pi,
    const float* __restrict__ pg, SMem& sm,
    float (&red)[3][4], int x0, int y0, double* __restrict__ sums) {
    const int tid = threadIdx.x;
    const int lane = tid & 63;
    const int wvi = tid >> 6;
    float sum_in = 0.f, sum_grad = 0.f, sum_ssim = 0.f;

    // ---- phase S: stage 10 raw rows per wave (self-contained per wave) ----
    {
        const int gx = x0 - 5 + lane;
        const int pr0 = 8 * wvi;               // plane rows pr0..pr0+9
        #pragma unroll
        for (int k = 0; k < 10; ++k) {
            int gy = y0 - 1 + pr0 + k;
            sm.praw[0][pr0 + k][lane] = ld<GUARD>(pg, gy, gx);
            sm.praw[1][pr0 + k][lane] = ld<GUARD>(pi, gy, gx);
            sm.praw[2][pr0 + k][lane] = ld<GUARD>(pv, gy, gx);
        }
    }
    // NO barrier: each wave reads back only rows+cols it wrote; DS ops within
    // a wave execute in order.

    // ---- sobel + intensity from LDS (independent throughput reads) ----
    {
        const int c = min(max(lane, 1), 62);   // clamped col (results masked)
        const bool colok = (lane >= 5) && (lane <= 58) &&
                           (!GUARD || (x0 - 5 + lane) < W);
        const int pr0 = 8 * wvi;
        float wn[3][3][3];                     // [img][rowslot][dx]
        #pragma unroll
        for (int k = 0; k < 2; ++k) {
            #pragma unroll
            for (int im = 0; im < 3; ++im) {
                wn[im][k][0] = sm.praw[im][pr0 + k][c - 1];
                wn[im][k][1] = sm.praw[im][pr0 + k][c];
                wn[im][k][2] = sm.praw[im][pr0 + k][c + 1];
            }
        }
        #pragma unroll
        for (int j = 0; j < 8; ++j) {
            const int s2 = (j + 2) % 3;
            #pragma unroll
            for (int im = 0; im < 3; ++im) {
                wn[im][s2][0] = sm.praw[im][pr0 + 2 + j][c - 1];
                wn[im][s2][1] = sm.praw[im][pr0 + 2 + j][c];
                wn[im][s2][2] = sm.praw[im][pr0 + 2 + j][c + 1];
            }
            const int s0 = j % 3, s1 = (j + 1) % 3;
            float mag[3];
            #pragma unroll
            for (int im = 0; im < 3; ++im) {
                float sgx = (wn[im][s0][2] - wn[im][s0][0]) +
                            2.f * (wn[im][s1][2] - wn[im][s1][0]) +
                            (wn[im][s2][2] - wn[im][s2][0]);
                float sgy = (wn[im][s0][0] - wn[im][s2][0]) +
                            2.f * (wn[im][s0][1] - wn[im][s2][1]) +
                            (wn[im][s0][2] - wn[im][s2][2]);
                mag[im] = fabsf(sgx) + fabsf(sgy);
            }
            if (colok) {
                sum_in   += fabsf(wn[0][s1][1] - fmaxf(wn[2][s1][1], wn[1][s1][1]));
                sum_grad += fabsf(mag[0] - fmaxf(mag[2], mag[1]));
            }
        }
    }
    __syncthreads();   // sobel reads done before vpass0 overwrites the union

    // ---- SSIM: two 4-quantity separable conv phases ----
    float resA[4][7], resB[4][7];
    vpass<GUARD, 0>(pg, pi, pv, sm, x0, y0, lane, wvi);
    __syncthreads();
    hpass(sm, resA, tid);
    __syncthreads();
    vpass<GUARD, 1>(pg, pi, pv, sm, x0, y0, lane, wvi);
    __syncthreads();
    hpass(sm, resB, tid);

    const int cch = tid >> 5;
    const int xb = (cch < 7) ? cch * 7 : 47;
    #pragma unroll
    for (int j = 0; j < 7; ++j) {
        bool valid = (cch < 7) || (j >= 2);     // drop chunk-7 duplicates
        if (GUARD) valid = valid && (x0 + xb + j < W);
        float m1 = resA[0][j], m2 = resA[1][j], m3 = resA[2][j];
        float sig1 = resA[3][j] - m1 * m1;
        float sig2 = resB[0][j] - m2 * m2;
        float sig3 = resB[1][j] - m3 * m3;
        float sg12 = resB[2][j] - m1 * m2;
        float sg13 = resB[3][j] - m1 * m3;
        float x2 = sqrtf(sig2);
        float x3 = sqrtf(sig3);
        float map12 = (2.f * sg12 + C2f) / (sig1 + sig2 + C2f);
        float map13 = (2.f * sg13 + C2f) / (sig1 + sig3 + C2f);
        // matches jnp.where(|x2| >= |x3|, map12, map13); NaN -> map13
        float m = (fabsf(x2) >= fabsf(x3)) ? map12 : map13;
        if (valid) sum_ssim += m;
    }

    // ---- reduce ----
    #pragma unroll
    for (int o = 32; o > 0; o >>= 1) {
        sum_in   += __shfl_down(sum_in, o);
        sum_grad += __shfl_down(sum_grad, o);
        sum_ssim += __shfl_down(sum_ssim, o);
    }
    if (lane == 0) { red[0][wvi] = sum_in; red[1][wvi] = sum_grad; red[2][wvi] = sum_ssim; }
    __syncthreads();
    if (tid == 0) {
        float a = 0.f, b = 0.f, c = 0.f;
        #pragma unroll
        for (int k = 0; k < 4; ++k) { a += red[0][k]; b += red[1][k]; c += red[2][k]; }
        atomicAdd(&sums[0], (double)a);
        atomicAdd(&sums[1], (double)b);
        atomicAdd(&sums[2], (double)c);
    }
}

__global__ __launch_bounds__(BLOCK) void fusion_main(
    const float* __restrict__ vis, const float* __restrict__ ir,
    const float* __restrict__ gen, double* __restrict__ sums) {
    __shared__ SMem sm;            // 33280 B -> 4 blocks/CU
    __shared__ float red[3][4];
    const size_t off = (size_t)blockIdx.z * (H * W);
    const int x0 = blockIdx.x * TX;
    const int y0 = blockIdx.y * TY;
    const float* pv = vis + off;
    const float* pi = ir + off;
    const float* pg = gen + off;
    // interior: x-range [x0-5, x0+58] in [0,512), y-range [y0-5, y0+36] in [0,512)
    bool interior = (blockIdx.x >= 1) && (blockIdx.x <= 8) &&
                    (blockIdx.y >= 1) && (blockIdx.y <= 14);
    if (interior) body<false>(pv, pi, pg, sm, red, x0, y0, sums);
    else          body<true>(pv, pi, pg, sm, red, x0, y0, sums);
}

__global__ void finalize(const double* __restrict__ sums, float* __restrict__ out) {
    const double inv = 1.0 / ((double)NB * H * W);
    out[0] = (float)(1.5 * sums[0] * inv);
    out[1] = (float)(0.5 * (1.0 - sums[2] * inv) + sums[1] * inv);
}

extern "C" void kernel_launch(void* const* d_in, const int* in_sizes, int n_in,
                              void* d_out, int out_size, void* d_ws, size_t ws_size,
                              hipStream_t stream) {
    const float* vis = (const float*)d_in[0];
    const float* ir  = (const float*)d_in[1];
    const float* gen = (const float*)d_in[2];
    float* out = (float*)d_out;
    double* sums = (double*)d_ws;

    hipMemsetAsync(d_ws, 0, 3 * sizeof(double), stream);
    dim3 grid(GRIDX, H / TY, NB);
    fusion_main<<<grid, BLOCK, 0, stream>>>(vis, ir, gen, sums);
    finalize<<<1, 1, 0, stream>>>(sums, out);
}